// Round 8
// baseline (202.865 us; speedup 1.0000x reference)
//
#include <hip/hip_runtime.h>
#include <hip/hip_bf16.h>

typedef __attribute__((ext_vector_type(8))) short short8;
typedef __attribute__((ext_vector_type(4))) short short4v;
typedef __attribute__((ext_vector_type(4))) float f32x4;
typedef __attribute__((ext_vector_type(2))) float f32x2;

namespace {
constexpr int kC = 256;
constexpr int kH = 4000;
constexpr int kNW = 800;
constexpr int kP = 5;
constexpr float kScale = 0.17677669529663687f; // 32^-0.5
constexpr int kTotalWin = 25600;

constexpr int WPB = 6;            // windows per block
constexpr int ROWS = WPB * kP;    // 30 (rows 30,31 zero-padded)
constexpr int NTHR = 512;         // 8 waves; wave == head

constexpr int WQKV_PACKED = 3 * 16 * 8 * 64 * 8;
constexpr int WOUT_PACKED = 16 * 8 * 64 * 8;

// LDS arena, 32KB:
//  R0 [0,16384)     : Xt -> q -> attn-out (32 rows x 512B, row-XOR swizzle)
//  RK [16384,32768) : k (32 rows x 512B, rows 30,31 stay zero)
constexpr int RKOFF = 16384;
constexpr int SM_TOTAL = 32768;
}

__device__ inline unsigned short f2bs(float f) {
  __hip_bfloat16 h = __float2bfloat16(f);
  return *reinterpret_cast<unsigned short*>(&h);
}

__device__ inline f32x4 mfma16(short4v a, short4v b, f32x4 c) {
#if __has_builtin(__builtin_amdgcn_mfma_f32_16x16x16bf16_1k)
  return __builtin_amdgcn_mfma_f32_16x16x16bf16_1k(a, b, c, 0, 0, 0);
#elif __has_builtin(__builtin_amdgcn_mfma_f32_16x16x16_bf16)
  return __builtin_amdgcn_mfma_f32_16x16x16_bf16(a, b, c, 0, 0, 0);
#else
  f32x4 d;
  asm("v_mfma_f32_16x16x16_bf16 %0, %1, %2, %3"
      : "=v"(d)
      : "v"(a), "v"(b), "v"(c));
  return d;
#endif
}

// Pack W_qkv (256x768) / W_out (256x256) f32 -> bf16 MFMA B-fragment order:
// [part][nt][kt][lane][8], B mapping: col = lane&15, k = (lane>>4)*8 + i.
__global__ void prep_weights(const float* __restrict__ Wqkv,
                             const float* __restrict__ Wout,
                             __hip_bfloat16* __restrict__ wq_p,
                             __hip_bfloat16* __restrict__ wo_p) {
  int idx = blockIdx.x * 256 + threadIdx.x;
  if (idx < WQKV_PACKED) {
    int i = idx & 7;
    int l = (idx >> 3) & 63;
    int kt = (idx >> 9) & 7;
    int nt = (idx >> 12) & 15;
    int part = idx >> 16;
    int k = kt * 32 + (l >> 4) * 8 + i;
    int col = part * 256 + nt * 16 + (l & 15);
    wq_p[idx] = __float2bfloat16(Wqkv[k * 768 + col]);
  }
  if (idx < WOUT_PACKED) {
    int i = idx & 7;
    int l = (idx >> 3) & 63;
    int kt = (idx >> 9) & 7;
    int nt = (idx >> 12) & 15;
    int k = kt * 32 + (l >> 4) * 8 + i;
    int col = nt * 16 + (l & 15);
    wo_p[idx] = __float2bfloat16(Wout[k * 256 + col]);
  }
}

// launch_bounds arg2 = CUDA-style min BLOCKS/CU on this toolchain
// ((512,4)->cap64, (512,6)->cap40+spills, (512,3)->cap85 no spills).
__global__ __launch_bounds__(NTHR, 3) void local_attn_kernel(
    const float* __restrict__ x, const short* __restrict__ wq_p,
    const short* __restrict__ wo_p, const float* __restrict__ b_out,
    float* __restrict__ g_out, float* __restrict__ g_attn) {
  __shared__ __align__(16) char smem[SM_TOTAL];

  const int tid = threadIdx.x;
  const int lane = tid & 63;
  const int wid = tid >> 6;
  const int g = lane >> 4;
  const int l15 = lane & 15;

  const int widx0 = blockIdx.x * WPB;
  const int nwin = min(WPB, kTotalWin - widx0);
  const int nrows = nwin * kP;

  // ---- P1: stage Xt bf16-swizzled into R0 (2 ch per 4B write), rows >=
  //          nrows zeroed (incl. 30,31). 128 cp x 32 rows = 4096 tasks.
#pragma unroll
  for (int pass = 0; pass < 8; ++pass) {
    int idx = pass * NTHR + tid;
    int cp = idx >> 5, hh = idx & 31;
    unsigned u = 0u;
    if (hh < nrows) {
      int wl = hh / kP, il = hh - wl * kP;
      int gw = widx0 + wl;
      int bb = gw / kNW;
      int hl = (gw - bb * kNW) * kP + il;
      const float* p = x + ((size_t)bb * kC + 2 * cp) * kH + hl;
      u = (unsigned)f2bs(p[0]) | ((unsigned)f2bs(p[kH]) << 16);
    }
    *(unsigned*)(smem + hh * 512 + ((cp * 4) ^ ((hh & 7) << 4))) = u;
  }
  __syncthreads();  // B1

  // ---- P2: GEMM1 qkv = Xt(32x256) @ Wqkv. k -> RK; v, q stay in registers.
  f32x4 acc_v[2][2];  // [ks-tile(m)][d-tile(n)] -- persists through PV
  {
    // k part (part=1)
    f32x4 acc[2][2];
#pragma unroll
    for (int m = 0; m < 2; ++m)
#pragma unroll
      for (int n = 0; n < 2; ++n) acc[m][n] = (f32x4){0.f, 0.f, 0.f, 0.f};
#pragma unroll
    for (int kt = 0; kt < 8; ++kt) {
      short8 a[2];
#pragma unroll
      for (int m = 0; m < 2; ++m) {
        int row = m * 16 + l15;
        int kb = kt * 64 + (g << 4);
        a[m] = *(const short8*)(smem + row * 512 + (kb ^ ((row & 7) << 4)));
      }
#pragma unroll
      for (int n = 0; n < 2; ++n) {
        short8 b = *(const short8*)(
            wq_p + ((((16 + wid * 2 + n) * 8 + kt) * 64 + lane) * 8));
#pragma unroll
        for (int m = 0; m < 2; ++m)
          acc[m][n] =
              __builtin_amdgcn_mfma_f32_16x16x32_bf16(a[m], b, acc[m][n], 0, 0, 0);
      }
    }
#pragma unroll
    for (int m = 0; m < 2; ++m)
#pragma unroll
      for (int n = 0; n < 2; ++n)
#pragma unroll
        for (int r = 0; r < 4; ++r) {
          int row = m * 16 + (g << 2) + r;
          if (row < ROWS) {
            int col = wid * 32 + n * 16 + l15;
            *(__hip_bfloat16*)(smem + RKOFF + row * 512 +
                               ((col * 2) ^ ((row & 7) << 4))) =
                __float2bfloat16(acc[m][n][r]);
          }
        }
    // v part (part=2) -> registers only
#pragma unroll
    for (int m = 0; m < 2; ++m)
#pragma unroll
      for (int n = 0; n < 2; ++n) acc_v[m][n] = (f32x4){0.f, 0.f, 0.f, 0.f};
#pragma unroll
    for (int kt = 0; kt < 8; ++kt) {
      short8 a[2];
#pragma unroll
      for (int m = 0; m < 2; ++m) {
        int row = m * 16 + l15;
        int kb = kt * 64 + (g << 4);
        a[m] = *(const short8*)(smem + row * 512 + (kb ^ ((row & 7) << 4)));
      }
#pragma unroll
      for (int n = 0; n < 2; ++n) {
        short8 b = *(const short8*)(
            wq_p + ((((32 + wid * 2 + n) * 8 + kt) * 64 + lane) * 8));
#pragma unroll
        for (int m = 0; m < 2; ++m)
          acc_v[m][n] = __builtin_amdgcn_mfma_f32_16x16x32_bf16(a[m], b,
                                                                acc_v[m][n], 0, 0, 0);
      }
    }
  }
  {  // q part (part=0): regs while Xt live, then -> R0
    f32x4 accq[2][2];
#pragma unroll
    for (int m = 0; m < 2; ++m)
#pragma unroll
      for (int n = 0; n < 2; ++n) accq[m][n] = (f32x4){0.f, 0.f, 0.f, 0.f};
#pragma unroll
    for (int kt = 0; kt < 8; ++kt) {
      short8 a[2];
#pragma unroll
      for (int m = 0; m < 2; ++m) {
        int row = m * 16 + l15;
        int kb = kt * 64 + (g << 4);
        a[m] = *(const short8*)(smem + row * 512 + (kb ^ ((row & 7) << 4)));
      }
#pragma unroll
      for (int n = 0; n < 2; ++n) {
        short8 b = *(const short8*)(
            wq_p + ((((wid * 2 + n) * 8 + kt) * 64 + lane) * 8));
#pragma unroll
        for (int m = 0; m < 2; ++m)
          accq[m][n] =
              __builtin_amdgcn_mfma_f32_16x16x32_bf16(a[m], b, accq[m][n], 0, 0, 0);
      }
    }
    __syncthreads();  // B2: Xt reads done
#pragma unroll
    for (int m = 0; m < 2; ++m)
#pragma unroll
      for (int n = 0; n < 2; ++n)
#pragma unroll
        for (int r = 0; r < 4; ++r) {
          int row = m * 16 + (g << 2) + r;
          if (row < ROWS) {
            int col = wid * 32 + n * 16 + l15;
            *(__hip_bfloat16*)(smem + row * 512 +
                               ((col * 2) ^ ((row & 7) << 4))) =
                __float2bfloat16(accq[m][n][r]);
          }
        }
  }
  __syncthreads();  // B3: q,k visible

  // ---- P3: attention, pure register dataflow (wave = head).
  {
    short8 kfa[2], qfb[2];
    const int cb = wid * 64 + (g << 4);
#pragma unroll
    for (int t = 0; t < 2; ++t) {
      int row = t * 16 + l15;
      int sw = (row & 7) << 4;
      kfa[t] = *(const short8*)(smem + RKOFF + row * 512 + (cb ^ sw));
      qfb[t] = *(const short8*)(smem + row * 512 + (cb ^ sw));
    }
    // S^T = K @ Q^T : sacc[mk][nq][r] = S[k=mk*16+g*4+r][q=nq*16+l15]
    f32x4 sacc[2][2];
#pragma unroll
    for (int mk = 0; mk < 2; ++mk)
#pragma unroll
      for (int nq = 0; nq < 2; ++nq)
        sacc[mk][nq] = __builtin_amdgcn_mfma_f32_16x16x32_bf16(
            kfa[mk], qfb[nq], (f32x4){0.f, 0.f, 0.f, 0.f}, 0, 0, 0);

    short4v pb[2][2];  // P^T B-frags [kblk][nq] -- same-lane from sacc
#pragma unroll
    for (int nq = 0; nq < 2; ++nq) {
      int q_abs = nq * 16 + l15;
      int w = q_abs / kP;
      int lo = w * kP;
      float psum = 0.f;
#pragma unroll
      for (int mk = 0; mk < 2; ++mk)
#pragma unroll
        for (int r = 0; r < 4; ++r) {
          int k = mk * 16 + (g << 2) + r;
          bool in = (q_abs < ROWS) && (k >= lo) && (k < lo + kP);
          float e = in ? __expf(sacc[mk][nq][r] * kScale) : 0.f;
          sacc[mk][nq][r] = e;
          psum += e;
        }
      psum += __shfl_xor(psum, 16);
      psum += __shfl_xor(psum, 32);
      float inv = psum > 0.f ? 1.f / psum : 0.f;
#pragma unroll
      for (int mk = 0; mk < 2; ++mk) {
        short4v t4;
#pragma unroll
        for (int r = 0; r < 4; ++r) {
          float pv = sacc[mk][nq][r] * inv;
          sacc[mk][nq][r] = pv;
          t4[r] = (short)f2bs(pv);
        }
        pb[mk][nq] = t4;
      }
      if (q_abs < nrows) {
        float* ap = g_attn + (size_t)(widx0 + w) * 200 + wid * 25 +
                    (q_abs - lo) * 5 - lo;
#pragma unroll
        for (int mk = 0; mk < 2; ++mk)
#pragma unroll
          for (int r = 0; r < 4; ++r) {
            int k = mk * 16 + (g << 2) + r;
            if (k >= lo && k < lo + kP) ap[k] = sacc[mk][nq][r];
          }
      }
    }
    // Vt A-frags: same-lane repack of acc_v (C-layout == K=16 A-layout)
    short4v av[2][2];  // [kblk][mt]
#pragma unroll
    for (int kb2 = 0; kb2 < 2; ++kb2)
#pragma unroll
      for (int mt = 0; mt < 2; ++mt) {
        short4v t4;
#pragma unroll
        for (int r = 0; r < 4; ++r) t4[r] = (short)f2bs(acc_v[kb2][mt][r]);
        av[kb2][mt] = t4;
      }
    // PV: out^T[d][q] via 2 chained K=16 MFMAs; packed 8B store into R0
#pragma unroll
    for (int mt = 0; mt < 2; ++mt)
#pragma unroll
      for (int nq = 0; nq < 2; ++nq) {
        f32x4 o = mfma16(av[0][mt], pb[0][nq], (f32x4){0.f, 0.f, 0.f, 0.f});
        o = mfma16(av[1][mt], pb[1][nq], o);
        int q_abs = nq * 16 + l15;
        if (q_abs < ROWS) {
          short4v o4;
#pragma unroll
          for (int r = 0; r < 4; ++r) o4[r] = (short)f2bs(o[r]);
          int byte = (wid * 64 + mt * 32 + g * 8) ^ ((q_abs & 7) << 4);
          *(short4v*)(smem + q_abs * 512 + byte) = o4;
        }
      }
  }
  __syncthreads();  // B4: all heads' attn-out in R0

  // ---- P4: GEMM2 out2 = attnout(32x256) @ Wout + b_out, direct global store
  f32x4 acc2[2][2];
#pragma unroll
  for (int m = 0; m < 2; ++m)
#pragma unroll
    for (int n = 0; n < 2; ++n) acc2[m][n] = (f32x4){0.f, 0.f, 0.f, 0.f};
#pragma unroll
  for (int kt = 0; kt < 8; ++kt) {
    short8 a[2];
#pragma unroll
    for (int m = 0; m < 2; ++m) {
      int row = m * 16 + l15;
      int kb = kt * 64 + (g << 4);
      a[m] = *(const short8*)(smem + row * 512 + (kb ^ ((row & 7) << 4)));
    }
#pragma unroll
    for (int n = 0; n < 2; ++n) {
      short8 b =
          *(const short8*)(wo_p + ((((wid * 2 + n) * 8 + kt) * 64 + lane) * 8));
#pragma unroll
      for (int m = 0; m < 2; ++m)
        acc2[m][n] =
            __builtin_amdgcn_mfma_f32_16x16x32_bf16(a[m], b, acc2[m][n], 0, 0, 0);
    }
  }
  {
    const int b0 = widx0 / kNW;
    const bool fast = (nrows == ROWS) && (b0 == (widx0 + WPB - 1) / kNW);
#pragma unroll
    for (int n = 0; n < 2; ++n) {
      int col = wid * 32 + n * 16 + l15;
      float bias = b_out[col];
      if (fast) {
        int h0 = (widx0 - b0 * kNW) * kP;
        float* op = g_out + ((size_t)b0 * kC + col) * kH + h0 + g * 4;
#pragma unroll
        for (int m = 0; m < 2; ++m) {
          // rows m*16 + g*4 + {0,1} always < 30; rows {2,3} junk iff m=1,g=3
          f32x2 v01 = {acc2[m][n][0] + bias, acc2[m][n][1] + bias};
          *(f32x2*)(op + m * 16) = v01;
          if (m * 16 + (g << 2) + 2 < ROWS) {
            f32x2 v23 = {acc2[m][n][2] + bias, acc2[m][n][3] + bias};
            *(f32x2*)(op + m * 16 + 2) = v23;
          }
        }
      } else {
#pragma unroll
        for (int m = 0; m < 2; ++m)
#pragma unroll
          for (int r = 0; r < 4; ++r) {
            int row = m * 16 + (g << 2) + r;
            if (row < nrows) {
              int gw = widx0 + row / kP;
              int bb = gw / kNW;
              int hl = (gw - bb * kNW) * kP + row % kP;
              g_out[((size_t)bb * kC + col) * kH + hl] = acc2[m][n][r] + bias;
            }
          }
      }
    }
  }
}

extern "C" void kernel_launch(void* const* d_in, const int* in_sizes, int n_in,
                              void* d_out, int out_size, void* d_ws,
                              size_t ws_size, hipStream_t stream) {
  const float* x = (const float*)d_in[0];
  const float* Wqkv = (const float*)d_in[1];
  const float* Wout = (const float*)d_in[2];
  const float* bout = (const float*)d_in[3];
  // d_in[4] (pos_embedding) provably cancels in softmax (row-constant bias).

  short* wq_p = (short*)d_ws;
  short* wo_p = wq_p + WQKV_PACKED;

  prep_weights<<<WQKV_PACKED / 256, 256, 0, stream>>>(
      Wqkv, Wout, (__hip_bfloat16*)wq_p, (__hip_bfloat16*)wo_p);

  float* g_out = (float*)d_out;
  float* g_attn = g_out + (size_t)32 * kC * kH;

  int nblocks = (kTotalWin + WPB - 1) / WPB;  // 4267
  local_attn_kernel<<<nblocks, NTHR, 0, stream>>>(x, wq_p, wo_p, bout, g_out,
                                                  g_attn);
}